// Round 4
// baseline (118.269 us; speedup 1.0000x reference)
//
#include <hip/hip_runtime.h>

#define BLOCK 256
#define PIX   32          // pixels per block
#define ESUB  8           // element subgroups; BLOCK = PIX * ESUB

// One block: 32 pixels x all elements for one (b,tx).
// Lanes map to pixels (gather locality); LDS transpose -> coalesced float2
// stores in (..., p, el, ch) layout. Output is FLOAT32 (268 MB), not bf16.
__global__ __launch_bounds__(BLOCK) void bf_tiled(
    const float* __restrict__ data,    // (batch,n_tx,n_el,n_ax,2) f32
    const float* __restrict__ grd,     // (P,3)
    const float* __restrict__ probe,   // (n_el,3)
    const float* __restrict__ itimes,  // (n_tx)
    const float* __restrict__ t0,      // (n_tx,n_el)
    const float* __restrict__ fs_p, const float* __restrict__ c_p,
    const float* __restrict__ fc_p, const float* __restrict__ fn_p,
    int n_tx, int n_el, int n_ax, int P,
    float2* __restrict__ out)
{
    __shared__ float2 tile[PIX][128];   // [pix][slot], slot = el ^ (pix&15)
    __shared__ float  smin[ESUB][PIX];
    __shared__ float  txd_s[PIX];

    const int t    = threadIdx.x;
    const int pix  = t & (PIX - 1);
    const int esub = t >> 5;            // 0..7
    const int p0   = blockIdx.x * PIX;
    const int p    = p0 + pix;
    const int tx   = blockIdx.y;
    const int b    = blockIdx.z;
    const int txb  = b * n_tx + tx;

    const float fs  = *fs_p;
    const float c   = *c_p;
    const float fcv = *fc_p;
    const float fn  = *fn_p;

    const float px = grd[3 * p + 0];
    const float pz = grd[3 * p + 2];

    // ---- Phase A: tx_dist = min_e (t0[tx,e]*c + |pix - el_e|), cooperative ----
    const int npass = n_el / ESUB;
    float mn = 3.4e38f;
    for (int k = 0; k < npass; ++k) {
        const int el = k * ESUB + esub;
        const float dx = px - probe[3 * el];
        mn = fminf(mn, t0[tx * n_el + el] * c + sqrtf(dx * dx + pz * pz));
    }
    smin[esub][pix] = mn;
    __syncthreads();
    if (t < PIX) {
        float m2 = smin[0][t];
#pragma unroll
        for (int k = 1; k < ESUB; ++k) m2 = fminf(m2, smin[k][t]);
        txd_s[t] = (m2 / c - itimes[tx]) * fs;   // samples
    }
    __syncthreads();

    const float txd     = txd_s[pix];
    const float half_ap = (pz / fn) * 0.5f;
    const float tdemod  = pz * 2.0f / c;
    const float twopifc = 6.28318530717958647692f * fcv;

    const float2* __restrict__ dat =
        (const float2*)data + (size_t)txb * n_el * n_ax;

    // ---- Phase B: per-element gather + lerp + phase rotation ----
    for (int k = 0; k < npass; ++k) {
        const int el = k * ESUB + esub;
        const float dx = px - probe[3 * el];
        const float m  = (fabsf(dx) <= half_ap) ? 1.0f : 0.0f;
        float2 res = make_float2(0.0f, 0.0f);
        if (__ballot(m != 0.0f) != 0ull) {
            if (m != 0.0f) {     // exec-masked: masked lanes skip loads + trig
                const float eld = sqrtf(dx * dx + pz * pz);
                const float del = txd + eld / c * fs;
                int i0 = (int)floorf(del);
                i0 = min(max(i0, 0), n_ax - 1);
                const int i1 = min(i0 + 1, n_ax - 1);
                const float w1 = del - (float)i0;
                const float w0 = (float)i1 - del;
                const float2 sA = dat[(size_t)el * n_ax + i0];
                const float2 sB = dat[(size_t)el * n_ax + i1];
                const float vi = w0 * sA.x + w1 * sB.x;
                const float vq = w0 * sA.y + w1 * sB.y;
                const float theta = twopifc * (del / fs - tdemod);
                const float ct = cosf(theta);
                const float st = sinf(theta);
                res = make_float2(vi * ct - vq * st, vq * ct + vi * st);
            }
        }
        tile[pix][el ^ (pix & 15)] = res;
    }
    __syncthreads();

    // ---- Store: coalesced float2 writes, (p, el) contiguous ----
    float2* __restrict__ op = out + ((size_t)txb * P + p0) * n_el;
    if (n_el == 128) {
        for (int f = t; f < PIX * 128; f += BLOCK) {
            const int pp = f >> 7;
            const int ee = f & 127;
            op[f] = tile[pp][ee ^ (pp & 15)];
        }
    } else {
        for (int f = t; f < PIX * n_el; f += BLOCK) {
            const int pp = f / n_el;
            const int ee = f - pp * n_el;
            op[f] = tile[pp][ee ^ (pp & 15)];
        }
    }
}

extern "C" void kernel_launch(void* const* d_in, const int* in_sizes, int n_in,
                              void* d_out, int out_size, void* d_ws, size_t ws_size,
                              hipStream_t stream) {
    (void)d_ws; (void)ws_size;
    const float* data   = (const float*)d_in[0];
    const float* grd    = (const float*)d_in[1];
    const float* probe  = (const float*)d_in[2];
    const float* itimes = (const float*)d_in[3];
    const float* t0     = (const float*)d_in[4];
    const float* fs_p   = (const float*)d_in[5];
    const float* c_p    = (const float*)d_in[6];
    const float* fc_p   = (const float*)d_in[7];
    // d_in[8] = fdemod (unused by reference path for n_ch==2)
    const float* fn_p   = (const float*)d_in[9];

    const int P    = in_sizes[1] / 3;
    const int n_el = in_sizes[2] / 3;
    const int n_tx = in_sizes[3];
    const long long batch =
        (long long)out_size / ((long long)n_tx * P * n_el * 2);
    const int n_ax =
        (int)(in_sizes[0] / (batch * (long long)n_tx * n_el * 2));

    dim3 g(P / PIX, n_tx, (unsigned int)batch);
    hipLaunchKernelGGL(bf_tiled, g, dim3(BLOCK), 0, stream,
                       data, grd, probe, itimes, t0,
                       fs_p, c_p, fc_p, fn_p,
                       n_tx, n_el, n_ax, P, (float2*)d_out);
}

// Round 6
// 83.218 us; speedup vs baseline: 1.4212x; 1.4212x over previous
//
#include <hip/hip_runtime.h>

#define BLOCK 256
#define PIX   32          // pixels per block
#define ESUB  8           // element subgroups; BLOCK = PIX * ESUB

typedef float f32x4 __attribute__((ext_vector_type(4)));
typedef float f32x2 __attribute__((ext_vector_type(2)));

// One block: 32 pixels x all elements for one (b,tx).
// Lanes map to pixels (gather locality); LDS transpose -> coalesced float4
// nontemporal stores in (..., p, el, ch) f32 layout.
__global__ __launch_bounds__(BLOCK) void bf_tiled(
    const float* __restrict__ data,    // (batch,n_tx,n_el,n_ax,2) f32
    const float* __restrict__ grd,     // (P,3)
    const float* __restrict__ probe,   // (n_el,3)
    const float* __restrict__ itimes,  // (n_tx)
    const float* __restrict__ t0,      // (n_tx,n_el)
    const float* __restrict__ fs_p, const float* __restrict__ c_p,
    const float* __restrict__ fc_p, const float* __restrict__ fn_p,
    int n_tx, int n_el, int n_ax, int P, int nx, int swz,
    float2* __restrict__ out)
{
    __shared__ __align__(16) float2 tile[PIX][128];  // slot = el ^ ((pix&15)<<1)
    __shared__ float smin[ESUB][PIX];
    __shared__ float txd_s[PIX];

    // ---- block-id decode (XCD-aware when swz==1) ----
    const int bid = blockIdx.x;
    int tx, pblk, b;
    if (swz) {
        const int g   = 8 / n_tx;          // XCD groups per tx
        const int xcd = bid & 7;
        const int s   = bid >> 3;
        tx = xcd % n_tx;
        const int idx = s * g + (xcd / n_tx);
        pblk = idx % nx;
        b    = idx / nx;
    } else {
        pblk = bid % nx;
        tx   = (bid / nx) % n_tx;
        b    = bid / (nx * n_tx);
    }
    const int txb = b * n_tx + tx;

    const int t    = threadIdx.x;
    const int pix  = t & (PIX - 1);
    const int esub = t >> 5;               // 0..7
    const int p0   = pblk * PIX;
    const int p    = p0 + pix;

    const float fs  = *fs_p;
    const float c   = *c_p;
    const float fcv = *fc_p;
    const float fn  = *fn_p;

    const float px = grd[3 * p + 0];
    const float pz = grd[3 * p + 2];

    // ---- Phase A: tx_dist = min_e (t0[tx,e]*c + |pix - el_e|) ----
    const int npass = n_el / ESUB;
    {
        float mn = 3.4e38f;
        for (int k = 0; k < npass; ++k) {
            const int el = k * ESUB + esub;
            const float dx = px - probe[3 * el];
            mn = fminf(mn, t0[tx * n_el + el] * c + sqrtf(dx * dx + pz * pz));
        }
        smin[esub][pix] = mn;
    }
    __syncthreads();
    if (t < PIX) {
        float m2 = smin[0][t];
#pragma unroll
        for (int k = 1; k < ESUB; ++k) m2 = fminf(m2, smin[k][t]);
        txd_s[t] = (m2 / c - itimes[tx]) * fs;   // samples
    }
    __syncthreads();

    // ---- loop-invariant algebra ----
    const float txd       = txd_s[pix];
    const float half_ap   = (pz / fn) * 0.5f;
    const float fs_over_c = fs / c;
    const float twopifc   = 6.28318530717958647692f * fcv;
    const float th_a      = twopifc / fs;              // theta = del*th_a - th_b
    const float th_b      = twopifc * (2.0f * pz / c);

    const float2* __restrict__ dat =
        (const float2*)data + (size_t)txb * n_el * n_ax;

    // ---- Phase B: gather + lerp + phase rotation ----
    for (int k = 0; k < npass; ++k) {
        const int el = k * ESUB + esub;
        const float dx = px - probe[3 * el];
        const float m  = (fabsf(dx) <= half_ap) ? 1.0f : 0.0f;
        float2 res = make_float2(0.0f, 0.0f);
        if (__ballot(m != 0.0f) != 0ull) {
            if (m != 0.0f) {
                const float eld = sqrtf(dx * dx + pz * pz);
                const float del = fmaf(eld, fs_over_c, txd);
                int i0 = (int)floorf(del);
                i0 = min(max(i0, 0), n_ax - 1);
                const int i1 = min(i0 + 1, n_ax - 1);
                const float w1 = del - (float)i0;
                const float w0 = (float)i1 - del;
                const float2 sA = dat[(size_t)el * n_ax + i0];
                const float2 sB = dat[(size_t)el * n_ax + i1];
                const float vi = w0 * sA.x + w1 * sB.x;
                const float vq = w0 * sA.y + w1 * sB.y;
                float st, ct;
                __sincosf(fmaf(del, th_a, -th_b), &st, &ct);
                res = make_float2(vi * ct - vq * st, vq * ct + vi * st);
            }
        }
        tile[pix][el ^ ((pix & 15) << 1)] = res;
    }
    __syncthreads();

    // ---- Store: coalesced float4 nontemporal writes ----
    float2* __restrict__ op = out + ((size_t)txb * P + p0) * n_el;
    if (n_el == 128) {
        const f32x4* __restrict__ t4 = (const f32x4*)&tile[0][0]; // 64 per pix row
        f32x4* __restrict__ o4 = (f32x4*)op;
        for (int f = t; f < PIX * 64; f += BLOCK) {
            const int pp = f >> 6;
            const int e4 = f & 63;
            __builtin_nontemporal_store(t4[pp * 64 + (e4 ^ (pp & 15))], &o4[f]);
        }
    } else {
        f32x2* __restrict__ o2 = (f32x2*)op;
        const f32x2* __restrict__ t2 = (const f32x2*)&tile[0][0];
        for (int f = t; f < PIX * n_el; f += BLOCK) {
            const int pp = f / n_el;
            const int ee = f - pp * n_el;
            __builtin_nontemporal_store(t2[pp * 128 + (ee ^ ((pp & 15) << 1))], &o2[f]);
        }
    }
}

extern "C" void kernel_launch(void* const* d_in, const int* in_sizes, int n_in,
                              void* d_out, int out_size, void* d_ws, size_t ws_size,
                              hipStream_t stream) {
    (void)d_ws; (void)ws_size;
    const float* data   = (const float*)d_in[0];
    const float* grd    = (const float*)d_in[1];
    const float* probe  = (const float*)d_in[2];
    const float* itimes = (const float*)d_in[3];
    const float* t0     = (const float*)d_in[4];
    const float* fs_p   = (const float*)d_in[5];
    const float* c_p    = (const float*)d_in[6];
    const float* fc_p   = (const float*)d_in[7];
    // d_in[8] = fdemod (unused by reference for n_ch==2)
    const float* fn_p   = (const float*)d_in[9];

    const int P    = in_sizes[1] / 3;
    const int n_el = in_sizes[2] / 3;
    const int n_tx = in_sizes[3];
    const long long batch =
        (long long)out_size / ((long long)n_tx * P * n_el * 2);
    const int n_ax =
        (int)(in_sizes[0] / (batch * (long long)n_tx * n_el * 2));

    const int nx   = P / PIX;                       // P % PIX == 0 (65536/32)
    const int nblk = nx * n_tx * (int)batch;
    const int swz  = (n_tx > 0 && 8 % n_tx == 0 && nblk % 8 == 0) ? 1 : 0;

    hipLaunchKernelGGL(bf_tiled, dim3(nblk), dim3(BLOCK), 0, stream,
                       data, grd, probe, itimes, t0,
                       fs_p, c_p, fc_p, fn_p,
                       n_tx, n_el, n_ax, P, nx, swz, (float2*)d_out);
}

// Round 7
// 62.498 us; speedup vs baseline: 1.8924x; 1.3315x over previous
//
#include <hip/hip_runtime.h>

#define BLOCK 256
#define PIX   32          // pixels per block
#define ESUB  8           // element subgroups; BLOCK = PIX * ESUB

typedef float f32x4 __attribute__((ext_vector_type(4)));
typedef float f32x2 __attribute__((ext_vector_type(2)));

__device__ __forceinline__ void decode_bid(int bid, int nx, int n_tx, int swz,
                                           int& tx, int& pblk, int& b) {
    if (swz) {
        const int g   = 8 / n_tx;          // XCD groups per tx
        const int xcd = bid & 7;
        const int s   = bid >> 3;
        tx = xcd % n_tx;
        const int idx = s * g + (xcd / n_tx);
        pblk = idx % nx;
        b    = idx / nx;
    } else {
        pblk = bid % nx;
        tx   = (bid / nx) % n_tx;
        b    = bid / (nx * n_tx);
    }
}

// Specialized n_el==128 kernel: register-cached geometry, revolutions-native
// trig, half-tile store pipelining (store half0 overlaps compute of half1).
__global__ __launch_bounds__(BLOCK) void bf128(
    const float* __restrict__ data,    // (batch,n_tx,128,n_ax,2) f32
    const float* __restrict__ grd,     // (P,3)
    const float* __restrict__ probe,   // (128,3)
    const float* __restrict__ itimes,  // (n_tx)
    const float* __restrict__ t0,      // (n_tx,128)
    const float* __restrict__ fs_p, const float* __restrict__ c_p,
    const float* __restrict__ fc_p, const float* __restrict__ fn_p,
    int n_tx, int n_ax, int P, int nx, int swz,
    float2* __restrict__ out)
{
    constexpr int NEL = 128, NPASS = 16, HALFP = 8;
    __shared__ __align__(16) float2 tile[PIX][NEL];  // slot = el ^ ((pix&15)<<1)
    __shared__ float smin[ESUB][PIX];
    __shared__ float txd_s[PIX];

    int tx, pblk, b;
    decode_bid(blockIdx.x, nx, n_tx, swz, tx, pblk, b);
    const int txb = b * n_tx + tx;

    const int t    = threadIdx.x;
    const int pix  = t & (PIX - 1);
    const int esub = t >> 5;
    const int p0   = pblk * PIX;
    const int p    = p0 + pix;

    const float fs  = *fs_p;
    const float c   = *c_p;
    const float fcv = *fc_p;
    const float fn  = *fn_p;

    const float px = grd[3 * p + 0];
    const float pz = grd[3 * p + 2];

    // ---- Phase A: per-el geometry (cached) + tx-distance min ----
    float dxr[NPASS], eldr[NPASS];
    {
        float mn = 3.4e38f;
#pragma unroll
        for (int k = 0; k < NPASS; ++k) {
            const int el = k * ESUB + esub;
            const float dx = px - probe[3 * el];
            const float eld = sqrtf(dx * dx + pz * pz);
            dxr[k] = dx;
            eldr[k] = eld;
            mn = fminf(mn, t0[tx * NEL + el] * c + eld);
        }
        smin[esub][pix] = mn;
    }
    __syncthreads();
    if (t < PIX) {
        float m2 = smin[0][t];
#pragma unroll
        for (int k = 1; k < ESUB; ++k) m2 = fminf(m2, smin[k][t]);
        txd_s[t] = (m2 / c - itimes[tx]) * fs;   // samples
    }
    __syncthreads();

    const float txd       = txd_s[pix];
    const float half_ap   = (pz / fn) * 0.5f;
    const float fs_over_c = fs / c;
    const float ka        = fcv / fs;            // rev = del*ka - revb
    const float revb      = fcv * (2.0f * pz / c);

    const float2* __restrict__ dat =
        (const float2*)data + (size_t)txb * NEL * n_ax;

#define BF_BODY(K0, K1)                                                     \
    _Pragma("unroll")                                                       \
    for (int k = (K0); k < (K1); ++k) {                                     \
        const int el = k * ESUB + esub;                                     \
        const float dx = dxr[k];                                            \
        const float m  = (fabsf(dx) <= half_ap) ? 1.0f : 0.0f;              \
        float2 res = make_float2(0.0f, 0.0f);                               \
        if (__ballot(m != 0.0f) != 0ull) {                                  \
            if (m != 0.0f) {                                                \
                const float del = fmaf(eldr[k], fs_over_c, txd);            \
                int i0 = (int)floorf(del);                                  \
                i0 = min(max(i0, 0), n_ax - 1);                             \
                const int i1 = min(i0 + 1, n_ax - 1);                       \
                const float w1 = del - (float)i0;                           \
                const float w0 = (float)i1 - del;                           \
                const float2 sA = dat[el * n_ax + i0];                      \
                const float2 sB = dat[el * n_ax + i1];                      \
                const float vi = w0 * sA.x + w1 * sB.x;                     \
                const float vq = w0 * sA.y + w1 * sB.y;                     \
                float rev = fmaf(del, ka, -revb);                           \
                rev -= floorf(rev);                                         \
                float st, ct;                                               \
                BF_SINCOS(rev, st, ct);                                     \
                res = make_float2(vi * ct - vq * st, vq * ct + vi * st);    \
            }                                                               \
        }                                                                   \
        tile[pix][el ^ ((pix & 15) << 1)] = res;                            \
    }

#if __has_builtin(__builtin_amdgcn_sinf) && __has_builtin(__builtin_amdgcn_cosf)
#define BF_SINCOS(r, s, cc) do { (s) = __builtin_amdgcn_sinf(r);            \
                                 (cc) = __builtin_amdgcn_cosf(r); } while (0)
#else
#define BF_SINCOS(r, s, cc) __sincosf((r) * 6.28318530717958647692f, &(s), &(cc))
#endif

    const f32x4* __restrict__ t4 = (const f32x4*)&tile[0][0]; // 64 per pix row
    f32x4* __restrict__ o4 = (f32x4*)(out + ((size_t)txb * P + p0) * NEL);

    // ---- half 0: compute els 0..63, store while half 1 computes ----
    BF_BODY(0, HALFP)
    __syncthreads();
#pragma unroll
    for (int f = t; f < PIX * 32; f += BLOCK) {
        const int pp = f >> 5;
        const int jj = f & 31;                       // float4 idx 0..31
        __builtin_nontemporal_store(t4[pp * 64 + (jj ^ (pp & 15))],
                                    &o4[pp * 64 + jj]);
    }
    // ---- half 1 ----
    BF_BODY(HALFP, NPASS)
    __syncthreads();
#pragma unroll
    for (int f = t; f < PIX * 32; f += BLOCK) {
        const int pp = f >> 5;
        const int jj = (f & 31) + 32;                // float4 idx 32..63
        __builtin_nontemporal_store(t4[pp * 64 + (jj ^ (pp & 15))],
                                    &o4[pp * 64 + jj]);
    }
#undef BF_BODY
#undef BF_SINCOS
}

// Generic fallback (round-6 structure, known good).
__global__ __launch_bounds__(BLOCK) void bf_tiled(
    const float* __restrict__ data, const float* __restrict__ grd,
    const float* __restrict__ probe, const float* __restrict__ itimes,
    const float* __restrict__ t0,
    const float* __restrict__ fs_p, const float* __restrict__ c_p,
    const float* __restrict__ fc_p, const float* __restrict__ fn_p,
    int n_tx, int n_el, int n_ax, int P, int nx, int swz,
    float2* __restrict__ out)
{
    __shared__ __align__(16) float2 tile[PIX][128];
    __shared__ float smin[ESUB][PIX];
    __shared__ float txd_s[PIX];

    int tx, pblk, b;
    decode_bid(blockIdx.x, nx, n_tx, swz, tx, pblk, b);
    const int txb = b * n_tx + tx;

    const int t    = threadIdx.x;
    const int pix  = t & (PIX - 1);
    const int esub = t >> 5;
    const int p0   = pblk * PIX;
    const int p    = p0 + pix;

    const float fs  = *fs_p;
    const float c   = *c_p;
    const float fcv = *fc_p;
    const float fn  = *fn_p;

    const float px = grd[3 * p + 0];
    const float pz = grd[3 * p + 2];

    const int npass = n_el / ESUB;
    {
        float mn = 3.4e38f;
        for (int k = 0; k < npass; ++k) {
            const int el = k * ESUB + esub;
            const float dx = px - probe[3 * el];
            mn = fminf(mn, t0[tx * n_el + el] * c + sqrtf(dx * dx + pz * pz));
        }
        smin[esub][pix] = mn;
    }
    __syncthreads();
    if (t < PIX) {
        float m2 = smin[0][t];
#pragma unroll
        for (int k = 1; k < ESUB; ++k) m2 = fminf(m2, smin[k][t]);
        txd_s[t] = (m2 / c - itimes[tx]) * fs;
    }
    __syncthreads();

    const float txd       = txd_s[pix];
    const float half_ap   = (pz / fn) * 0.5f;
    const float fs_over_c = fs / c;
    const float twopifc   = 6.28318530717958647692f * fcv;
    const float th_a      = twopifc / fs;
    const float th_b      = twopifc * (2.0f * pz / c);

    const float2* __restrict__ dat =
        (const float2*)data + (size_t)txb * n_el * n_ax;

    for (int k = 0; k < npass; ++k) {
        const int el = k * ESUB + esub;
        const float dx = px - probe[3 * el];
        const float m  = (fabsf(dx) <= half_ap) ? 1.0f : 0.0f;
        float2 res = make_float2(0.0f, 0.0f);
        if (__ballot(m != 0.0f) != 0ull) {
            if (m != 0.0f) {
                const float eld = sqrtf(dx * dx + pz * pz);
                const float del = fmaf(eld, fs_over_c, txd);
                int i0 = (int)floorf(del);
                i0 = min(max(i0, 0), n_ax - 1);
                const int i1 = min(i0 + 1, n_ax - 1);
                const float w1 = del - (float)i0;
                const float w0 = (float)i1 - del;
                const float2 sA = dat[(size_t)el * n_ax + i0];
                const float2 sB = dat[(size_t)el * n_ax + i1];
                const float vi = w0 * sA.x + w1 * sB.x;
                const float vq = w0 * sA.y + w1 * sB.y;
                float st, ct;
                __sincosf(fmaf(del, th_a, -th_b), &st, &ct);
                res = make_float2(vi * ct - vq * st, vq * ct + vi * st);
            }
        }
        tile[pix][el ^ ((pix & 15) << 1)] = res;
    }
    __syncthreads();

    float2* __restrict__ op = out + ((size_t)txb * P + p0) * n_el;
    f32x2* __restrict__ o2 = (f32x2*)op;
    const f32x2* __restrict__ t2 = (const f32x2*)&tile[0][0];
    for (int f = t; f < PIX * n_el; f += BLOCK) {
        const int pp = f / n_el;
        const int ee = f - pp * n_el;
        __builtin_nontemporal_store(t2[pp * 128 + (ee ^ ((pp & 15) << 1))], &o2[f]);
    }
}

extern "C" void kernel_launch(void* const* d_in, const int* in_sizes, int n_in,
                              void* d_out, int out_size, void* d_ws, size_t ws_size,
                              hipStream_t stream) {
    (void)d_ws; (void)ws_size;
    const float* data   = (const float*)d_in[0];
    const float* grd    = (const float*)d_in[1];
    const float* probe  = (const float*)d_in[2];
    const float* itimes = (const float*)d_in[3];
    const float* t0     = (const float*)d_in[4];
    const float* fs_p   = (const float*)d_in[5];
    const float* c_p    = (const float*)d_in[6];
    const float* fc_p   = (const float*)d_in[7];
    // d_in[8] = fdemod (unused by reference for n_ch==2)
    const float* fn_p   = (const float*)d_in[9];

    const int P    = in_sizes[1] / 3;
    const int n_el = in_sizes[2] / 3;
    const int n_tx = in_sizes[3];
    const long long batch =
        (long long)out_size / ((long long)n_tx * P * n_el * 2);
    const int n_ax =
        (int)(in_sizes[0] / (batch * (long long)n_tx * n_el * 2));

    const int nx   = P / PIX;
    const int nblk = nx * n_tx * (int)batch;
    const int swz  = (n_tx > 0 && 8 % n_tx == 0 && nblk % 8 == 0) ? 1 : 0;

    if (n_el == 128 && P % PIX == 0) {
        hipLaunchKernelGGL(bf128, dim3(nblk), dim3(BLOCK), 0, stream,
                           data, grd, probe, itimes, t0,
                           fs_p, c_p, fc_p, fn_p,
                           n_tx, n_ax, P, nx, swz, (float2*)d_out);
    } else {
        hipLaunchKernelGGL(bf_tiled, dim3(nblk), dim3(BLOCK), 0, stream,
                           data, grd, probe, itimes, t0,
                           fs_p, c_p, fc_p, fn_p,
                           n_tx, n_el, n_ax, P, nx, swz, (float2*)d_out);
    }
}

// Round 8
// 59.691 us; speedup vs baseline: 1.9813x; 1.0470x over previous
//
#include <hip/hip_runtime.h>

#define BLOCK 256
// specialized kernel tile
#define PIX   16          // pixels per block (16KB tile -> 8 blocks/CU)
#define ESUB  16          // element subgroups; BLOCK = PIX * ESUB
// generic fallback tile (round-6 verified constants)
#define PIXG  32
#define ESUBG 8

typedef float f32x4 __attribute__((ext_vector_type(4)));
typedef float f32x2 __attribute__((ext_vector_type(2)));

__device__ __forceinline__ void decode_bid(int bid, int nx, int n_tx, int swz,
                                           int& tx, int& pblk, int& b) {
    if (swz) {
        const int g   = 8 / n_tx;          // XCD groups per tx
        const int xcd = bid & 7;
        const int s   = bid >> 3;
        tx = xcd % n_tx;
        const int idx = s * g + (xcd / n_tx);
        pblk = idx % nx;
        b    = idx / nx;
    } else {
        pblk = bid % nx;
        tx   = (bid / nx) % n_tx;
        b    = bid / (nx * n_tx);
    }
}

// Specialized n_el==128 kernel: 16-pixel tile (8 blocks/CU), register-cached
// geometry, revolutions-native trig, half-tile store pipelining.
__global__ __launch_bounds__(BLOCK) void bf128(
    const float* __restrict__ data,    // (batch,n_tx,128,n_ax,2) f32
    const float* __restrict__ grd,     // (P,3)
    const float* __restrict__ probe,   // (128,3)
    const float* __restrict__ itimes,  // (n_tx)
    const float* __restrict__ t0,      // (n_tx,128)
    const float* __restrict__ fs_p, const float* __restrict__ c_p,
    const float* __restrict__ fc_p, const float* __restrict__ fn_p,
    int n_tx, int n_ax, int P, int nx, int swz,
    float2* __restrict__ out)
{
    constexpr int NEL = 128, NPASS = 8, HALFP = 4;
    __shared__ __align__(16) float2 tile[PIX][NEL];  // slot = el ^ (pix<<1)
    __shared__ float smin[ESUB][PIX];
    __shared__ float txd_s[PIX];

    int tx, pblk, b;
    decode_bid(blockIdx.x, nx, n_tx, swz, tx, pblk, b);
    const int txb = b * n_tx + tx;

    const int t    = threadIdx.x;
    const int pix  = t & (PIX - 1);
    const int esub = t >> 4;               // 0..15
    const int p0   = pblk * PIX;
    const int p    = p0 + pix;

    const float fs  = *fs_p;
    const float c   = *c_p;
    const float fcv = *fc_p;
    const float fn  = *fn_p;

    const float px = grd[3 * p + 0];
    const float pz = grd[3 * p + 2];

    // ---- Phase A: per-el geometry (cached) + tx-distance min ----
    float dxr[NPASS], eldr[NPASS];
    {
        float mn = 3.4e38f;
#pragma unroll
        for (int k = 0; k < NPASS; ++k) {
            const int el = k * ESUB + esub;
            const float dx = px - probe[3 * el];
            const float eld = sqrtf(dx * dx + pz * pz);
            dxr[k] = dx;
            eldr[k] = eld;
            mn = fminf(mn, t0[tx * NEL + el] * c + eld);
        }
        smin[esub][pix] = mn;
    }
    __syncthreads();
    if (t < PIX) {
        float m2 = smin[0][t];
#pragma unroll
        for (int k = 1; k < ESUB; ++k) m2 = fminf(m2, smin[k][t]);
        txd_s[t] = (m2 / c - itimes[tx]) * fs;   // samples
    }
    __syncthreads();

    const float txd       = txd_s[pix];
    const float half_ap   = (pz / fn) * 0.5f;
    const float fs_over_c = fs / c;
    const float ka        = fcv / fs;            // rev = del*ka - revb
    const float revb      = fcv * (2.0f * pz / c);

    const float2* __restrict__ dat =
        (const float2*)data + (size_t)txb * NEL * n_ax;

#if __has_builtin(__builtin_amdgcn_sinf) && __has_builtin(__builtin_amdgcn_cosf)
#define BF_SINCOS(r, s, cc) do { (s) = __builtin_amdgcn_sinf(r);            \
                                 (cc) = __builtin_amdgcn_cosf(r); } while (0)
#else
#define BF_SINCOS(r, s, cc) __sincosf((r) * 6.28318530717958647692f, &(s), &(cc))
#endif

#define BF_BODY(K0, K1)                                                     \
    _Pragma("unroll")                                                       \
    for (int k = (K0); k < (K1); ++k) {                                     \
        const int el = k * ESUB + esub;                                     \
        const float dx = dxr[k];                                            \
        const float m  = (fabsf(dx) <= half_ap) ? 1.0f : 0.0f;              \
        float2 res = make_float2(0.0f, 0.0f);                               \
        if (__ballot(m != 0.0f) != 0ull) {                                  \
            if (m != 0.0f) {                                                \
                const float del = fmaf(eldr[k], fs_over_c, txd);            \
                int i0 = (int)floorf(del);                                  \
                i0 = min(max(i0, 0), n_ax - 1);                             \
                const int i1 = min(i0 + 1, n_ax - 1);                       \
                const float w1 = del - (float)i0;                           \
                const float w0 = (float)i1 - del;                           \
                const float2 sA = dat[el * n_ax + i0];                      \
                const float2 sB = dat[el * n_ax + i1];                      \
                const float vi = w0 * sA.x + w1 * sB.x;                     \
                const float vq = w0 * sA.y + w1 * sB.y;                     \
                float rev = fmaf(del, ka, -revb);                           \
                rev -= floorf(rev);                                         \
                float st, ct;                                               \
                BF_SINCOS(rev, st, ct);                                     \
                res = make_float2(vi * ct - vq * st, vq * ct + vi * st);    \
            }                                                               \
        }                                                                   \
        tile[pix][el ^ (pix << 1)] = res;                                   \
    }

    const f32x4* __restrict__ t4 = (const f32x4*)&tile[0][0]; // 64 per pix row
    f32x4* __restrict__ o4 = (f32x4*)(out + ((size_t)txb * P + p0) * NEL);

    // ---- half 0: compute els 0..63; store overlaps half-1 compute ----
    BF_BODY(0, HALFP)
    __syncthreads();
#pragma unroll
    for (int f = t; f < PIX * 32; f += BLOCK) {
        const int pp = f >> 5;
        const int jj = f & 31;                       // float4 idx 0..31
        __builtin_nontemporal_store(t4[pp * 64 + (jj ^ pp)],
                                    &o4[pp * 64 + jj]);
    }
    // ---- half 1 ----
    BF_BODY(HALFP, NPASS)
    __syncthreads();
#pragma unroll
    for (int f = t; f < PIX * 32; f += BLOCK) {
        const int pp = f >> 5;
        const int jj = (f & 31) + 32;                // float4 idx 32..63
        __builtin_nontemporal_store(t4[pp * 64 + (jj ^ pp)],
                                    &o4[pp * 64 + jj]);
    }
#undef BF_BODY
#undef BF_SINCOS
}

// Generic fallback (round-6 structure, known good, own constants).
__global__ __launch_bounds__(BLOCK) void bf_tiled(
    const float* __restrict__ data, const float* __restrict__ grd,
    const float* __restrict__ probe, const float* __restrict__ itimes,
    const float* __restrict__ t0,
    const float* __restrict__ fs_p, const float* __restrict__ c_p,
    const float* __restrict__ fc_p, const float* __restrict__ fn_p,
    int n_tx, int n_el, int n_ax, int P, int nx, int swz,
    float2* __restrict__ out)
{
    __shared__ __align__(16) float2 tile[PIXG][128];
    __shared__ float smin[ESUBG][PIXG];
    __shared__ float txd_s[PIXG];

    int tx, pblk, b;
    decode_bid(blockIdx.x, nx, n_tx, swz, tx, pblk, b);
    const int txb = b * n_tx + tx;

    const int t    = threadIdx.x;
    const int pix  = t & (PIXG - 1);
    const int esub = t >> 5;
    const int p0   = pblk * PIXG;
    const int p    = p0 + pix;

    const float fs  = *fs_p;
    const float c   = *c_p;
    const float fcv = *fc_p;
    const float fn  = *fn_p;

    const float px = grd[3 * p + 0];
    const float pz = grd[3 * p + 2];

    const int npass = n_el / ESUBG;
    {
        float mn = 3.4e38f;
        for (int k = 0; k < npass; ++k) {
            const int el = k * ESUBG + esub;
            const float dx = px - probe[3 * el];
            mn = fminf(mn, t0[tx * n_el + el] * c + sqrtf(dx * dx + pz * pz));
        }
        smin[esub][pix] = mn;
    }
    __syncthreads();
    if (t < PIXG) {
        float m2 = smin[0][t];
#pragma unroll
        for (int k = 1; k < ESUBG; ++k) m2 = fminf(m2, smin[k][t]);
        txd_s[t] = (m2 / c - itimes[tx]) * fs;
    }
    __syncthreads();

    const float txd       = txd_s[pix];
    const float half_ap   = (pz / fn) * 0.5f;
    const float fs_over_c = fs / c;
    const float twopifc   = 6.28318530717958647692f * fcv;
    const float th_a      = twopifc / fs;
    const float th_b      = twopifc * (2.0f * pz / c);

    const float2* __restrict__ dat =
        (const float2*)data + (size_t)txb * n_el * n_ax;

    for (int k = 0; k < npass; ++k) {
        const int el = k * ESUBG + esub;
        const float dx = px - probe[3 * el];
        const float m  = (fabsf(dx) <= half_ap) ? 1.0f : 0.0f;
        float2 res = make_float2(0.0f, 0.0f);
        if (__ballot(m != 0.0f) != 0ull) {
            if (m != 0.0f) {
                const float eld = sqrtf(dx * dx + pz * pz);
                const float del = fmaf(eld, fs_over_c, txd);
                int i0 = (int)floorf(del);
                i0 = min(max(i0, 0), n_ax - 1);
                const int i1 = min(i0 + 1, n_ax - 1);
                const float w1 = del - (float)i0;
                const float w0 = (float)i1 - del;
                const float2 sA = dat[(size_t)el * n_ax + i0];
                const float2 sB = dat[(size_t)el * n_ax + i1];
                const float vi = w0 * sA.x + w1 * sB.x;
                const float vq = w0 * sA.y + w1 * sB.y;
                float st, ct;
                __sincosf(fmaf(del, th_a, -th_b), &st, &ct);
                res = make_float2(vi * ct - vq * st, vq * ct + vi * st);
            }
        }
        tile[pix][el ^ ((pix & 15) << 1)] = res;
    }
    __syncthreads();

    float2* __restrict__ op = out + ((size_t)txb * P + p0) * n_el;
    f32x2* __restrict__ o2 = (f32x2*)op;
    const f32x2* __restrict__ t2 = (const f32x2*)&tile[0][0];
    for (int f = t; f < PIXG * n_el; f += BLOCK) {
        const int pp = f / n_el;
        const int ee = f - pp * n_el;
        __builtin_nontemporal_store(t2[pp * 128 + (ee ^ ((pp & 15) << 1))], &o2[f]);
    }
}

extern "C" void kernel_launch(void* const* d_in, const int* in_sizes, int n_in,
                              void* d_out, int out_size, void* d_ws, size_t ws_size,
                              hipStream_t stream) {
    (void)d_ws; (void)ws_size;
    const float* data   = (const float*)d_in[0];
    const float* grd    = (const float*)d_in[1];
    const float* probe  = (const float*)d_in[2];
    const float* itimes = (const float*)d_in[3];
    const float* t0     = (const float*)d_in[4];
    const float* fs_p   = (const float*)d_in[5];
    const float* c_p    = (const float*)d_in[6];
    const float* fc_p   = (const float*)d_in[7];
    // d_in[8] = fdemod (unused by reference for n_ch==2)
    const float* fn_p   = (const float*)d_in[9];

    const int P    = in_sizes[1] / 3;
    const int n_el = in_sizes[2] / 3;
    const int n_tx = in_sizes[3];
    const long long batch =
        (long long)out_size / ((long long)n_tx * P * n_el * 2);
    const int n_ax =
        (int)(in_sizes[0] / (batch * (long long)n_tx * n_el * 2));

    if (n_el == 128 && P % PIX == 0) {
        const int nx   = P / PIX;
        const int nblk = nx * n_tx * (int)batch;
        const int swz  = (n_tx > 0 && 8 % n_tx == 0 && nblk % 8 == 0) ? 1 : 0;
        hipLaunchKernelGGL(bf128, dim3(nblk), dim3(BLOCK), 0, stream,
                           data, grd, probe, itimes, t0,
                           fs_p, c_p, fc_p, fn_p,
                           n_tx, n_ax, P, nx, swz, (float2*)d_out);
    } else {
        const int nx   = P / PIXG;
        const int nblk = nx * n_tx * (int)batch;
        const int swz  = (n_tx > 0 && 8 % n_tx == 0 && nblk % 8 == 0) ? 1 : 0;
        hipLaunchKernelGGL(bf_tiled, dim3(nblk), dim3(BLOCK), 0, stream,
                           data, grd, probe, itimes, t0,
                           fs_p, c_p, fc_p, fn_p,
                           n_tx, n_el, n_ax, P, nx, swz, (float2*)d_out);
    }
}